// Round 14
// baseline (2924.210 us; speedup 1.0000x reference)
//
#include <hip/hip_runtime.h>
#include <hip/hip_bf16.h>
#include <hip/hip_fp8.h>

// Problem constants (fixed by the bench: B=32, T0=50, F=171, H=1024, G=300)
#define Bn   32
#define Fdim 171
#define XPAD 256             // x-region padded to 16 tiles of 16 (conditioned phase)
#define Hdim 1024
#define NG   4096            // 4*H gate rows
#define K1K  1536            // layer1 conditioned K padded (x|pad|h|pad)
#define K1g  2048            // layer1 generative K = H(h2 via Wcomb) + H(h0)
#define K2c  2048            // layer2/3 K = 2H
#define KDd  1024            // decoder K = H
#define WDR  176             // decoder rows padded 171 -> 176
#define BPL  128             // blocks per layer (32 gate rows each)
#define NWRK (3 * BPL)       // 384 worker blocks
#define NDEC 11              // dedicated decoder blocks
#define S1e  (80 * 512)      // ab1 slot BYTES (fp8, tiled [80][32][16], k<1280)
#define S2e  (128 * 512)     // ab2/ab3 slot BYTES (tiled [128][32][16])

// fp8 scaling: weights *64, activations *16, both exact powers of 2.
#define SW    64.0f
#define SA    16.0f
#define INVS  (1.0f / (SW * SA))

typedef __attribute__((ext_vector_type(4))) float f32x4;
typedef __attribute__((ext_vector_type(2))) long lx2;
typedef unsigned char fp8;

// ---------------- static workspace layout (bytes); ab buffers are tail ----
#define ALIGN256(x) ((((size_t)(x)) + 255) & ~(size_t)255)
constexpr size_t OFF_W1  = 0;                                       // packed 4096*1536
constexpr size_t OFF_W1G = ALIGN256(OFF_W1 + (size_t)NG * K1K);     // packed 4096*2048
constexpr size_t OFF_W2  = ALIGN256(OFF_W1G + (size_t)NG * K1g);
constexpr size_t OFF_W3  = ALIGN256(OFF_W2 + (size_t)NG * K2c);
constexpr size_t OFF_WD  = ALIGN256(OFF_W3 + (size_t)NG * K2c);     // row-linear
constexpr size_t OFF_B1  = ALIGN256(OFF_WD + (size_t)WDR * KDd);
constexpr size_t OFF_B1G = ALIGN256(OFF_B1 + (size_t)NG * 4);
constexpr size_t OFF_B2  = ALIGN256(OFF_B1G + (size_t)NG * 4);
constexpr size_t OFF_B3  = ALIGN256(OFF_B2 + (size_t)NG * 4);
constexpr size_t OFF_BD  = ALIGN256(OFF_B3 + (size_t)NG * 4);
constexpr size_t OFF_CB  = ALIGN256(OFF_BD + (size_t)WDR * 4);
constexpr size_t OFF_BAR = ALIGN256(OFF_CB + (size_t)3 * Bn * Hdim * 4);
constexpr size_t OFF_AB1 = ALIGN256(OFF_BAR + 32768);   // bar region: 8192 u32

// flags: one u32 per 64B line. flag[b]=t+1 <=> worker b finished step t.
#define FLG(i)   ((i) * 16)                       // 384 worker flags
#define LPW(l,m) (6144 + ((l) * 8 + (m)) * 16)    // per-layer progress, 8 mirrors

// new packed gate-row order: pr = ut2*32 + g*8 + u  <->  orig row g*1024 + ut2*8 + u
__device__ __forceinline__ int orig_row2(int pr) {
    int ut2 = pr >> 5, g = (pr >> 3) & 3, u = pr & 7;
    return g * 1024 + ut2 * 8 + u;
}

__device__ __forceinline__ float sigm(float x) { return 1.f / (1.f + __expf(-x)); }
__device__ __forceinline__ float ftanh(float x) {   // overflow-safe fast tanh
    float e = __expf(-2.f * fabsf(x));
    float t = (1.f - e) / (1.f + e);
    return x >= 0.f ? t : -t;
}

__device__ __forceinline__ unsigned char f2fp8(float x) {  // OCP e4m3, RNE+sat
    __hip_fp8_e4m3 q(x);
    return (unsigned char)q.__x;
}

__device__ __forceinline__ long ld8b(const fp8* p) {   // plain cached 8B load
    return *reinterpret_cast<const long*>(p);
}
// Coherent write-through ops (agent scope, relaxed): no cache-wide maintenance.
__device__ __forceinline__ void st1c(fp8* p, unsigned char v) {
    __hip_atomic_store((unsigned char*)p, v, __ATOMIC_RELAXED, __HIP_MEMORY_SCOPE_AGENT);
}
__device__ __forceinline__ void stu64(unsigned long long* p, unsigned long long v) {
    __hip_atomic_store(p, v, __ATOMIC_RELAXED, __HIP_MEMORY_SCOPE_AGENT);
}
__device__ __forceinline__ unsigned ldflag(const unsigned* p) {
    return __hip_atomic_load(p, __ATOMIC_RELAXED, __HIP_MEMORY_SCOPE_AGENT);
}
__device__ __forceinline__ void stflag(unsigned* p, unsigned v) {
    __hip_atomic_store(p, v, __ATOMIC_RELAXED, __HIP_MEMORY_SCOPE_AGENT);
}
__device__ __forceinline__ f32x4 mfma8(long a, long b, f32x4 c) {
    return __builtin_amdgcn_mfma_f32_16x16x32_fp8_fp8(a, b, c, 0, 0, 0);
}

// per-wave LP poll: lane0 waits LP[la]>=tgt, lane1 waits LP[lb]>=tgt (mirror m)
__device__ __forceinline__ void pollLP(unsigned* bar, int la, int lb,
                                       unsigned tgt, int lane, int m) {
    int tries = 0;
    for (;;) {
        bool ok = true;
        if (lane == 0) ok = (ldflag(&bar[LPW(la, m)]) >= tgt);
        else if (lane == 1 && lb >= 0) ok = (ldflag(&bar[LPW(lb, m)]) >= tgt);
        if (__all(ok)) break;
        if (tries < 4) __builtin_amdgcn_s_sleep(1);
        else           __builtin_amdgcn_s_sleep(4);
        ++tries;
    }
    asm volatile("" ::: "memory");
}

// A-fragment loads from tiled [k/16][b][16] fp8 state
template <int NF>
__device__ __forceinline__ void aload(const fp8* __restrict__ As, int k0,
                                      int col, int kb8, long (&a0)[NF], long (&a1)[NF]) {
#pragma unroll
    for (int i = 0; i < NF; ++i) {
        int k = k0 + i * 32 + kb8;
        const fp8* ap = As + (size_t)(k >> 4) * 512 + (k & 15);
        a0[i] = ld8b(ap + col * 16);
        a1[i] = ld8b(ap + (col + 16) * 16);
    }
}

// packed weight stream (4-wave, 32-row tiles): per (i2,q2) ONE 16B/lane load
// = 1KB/wave fully-used (two K-chunks per instruction).
template <int NP>
__device__ __forceinline__ void wstream_pk(const fp8* __restrict__ wwave, int lane,
                                           const long (&a0)[2 * NP],
                                           const long (&a1)[2 * NP],
                                           f32x4 (&acc)[2][2]) {
#pragma unroll
    for (int i2 = 0; i2 < NP; ++i2) {
        const fp8* p = wwave + i2 * 2048 + lane * 16;
#pragma unroll
        for (int q2 = 0; q2 < 2; ++q2) {
            lx2 wv = *reinterpret_cast<const lx2*>(p + q2 * 1024);
            acc[0][q2] = mfma8(a0[2 * i2],     wv[0], acc[0][q2]);
            acc[1][q2] = mfma8(a1[2 * i2],     wv[0], acc[1][q2]);
            acc[0][q2] = mfma8(a0[2 * i2 + 1], wv[1], acc[0][q2]);
            acc[1][q2] = mfma8(a1[2 * i2 + 1], wv[1], acc[1][q2]);
        }
    }
}

// ---------------- prep kernels ----------------
// fragment-order packer for 32-row tiles / 4 waves.
// idx = ut2*32*Kpk + w*8*Kpk + i2*2048 + q2*1024 + lane*16 + b
//  row = q2*16 + (lane&15) -> g = q2*2 + (lane&15)/8, u = (lane&15)%8
//  k = w*(Kpk/4) + (2*i2 + (b>>3))*32 + (lane>>4)*8 + (b&7)
// mode 0: W1 cond (x|pad|h|pad); 1: W1G (Wcomb|Whh1); 2: W2/W3 (Wih|Whh)
__global__ void k_pack_pk(int mode, const float* Wih, const float* Whh,
                          const float* Wd, fp8* dst, int Kpk) {
    const size_t n = (size_t)NG * Kpk;
    const int kq = Kpk >> 2;
    for (size_t idx = (size_t)blockIdx.x * blockDim.x + threadIdx.x; idx < n;
         idx += (size_t)gridDim.x * blockDim.x) {
        int ut2 = (int)(idx / ((size_t)32 * Kpk));
        int rem = (int)(idx % ((size_t)32 * Kpk));
        int w = rem / (8 * Kpk);
        int rem2 = rem % (8 * Kpk);
        int i2 = rem2 >> 11;
        int q2 = (rem2 >> 10) & 1;
        int lane = (rem2 >> 4) & 63;
        int b = rem2 & 15;
        int rr = lane & 15;
        int g = q2 * 2 + (rr >> 3), u = rr & 7;
        int ro = g * 1024 + ut2 * 8 + u;
        int k = w * kq + (2 * i2 + (b >> 3)) * 32 + ((lane >> 4) << 3) + (b & 7);
        float v = 0.f;
        if (mode == 0) {
            if (k < Fdim) v = Wih[(size_t)ro * Fdim + k];
            else if (k >= XPAD && k < XPAD + Hdim) v = Whh[(size_t)ro * Hdim + (k - XPAD)];
        } else if (mode == 1) {
            if (k < Hdim) {
                float a = 0.f;
                for (int f = 0; f < Fdim; ++f)
                    a += Wih[(size_t)ro * Fdim + f] * Wd[(size_t)f * KDd + k];
                v = a;
            } else {
                v = Whh[(size_t)ro * Hdim + (k - 1024)];
            }
        } else {
            v = (k < Hdim) ? Wih[(size_t)ro * Hdim + k]
                           : Whh[(size_t)ro * Hdim + (k - Hdim)];
        }
        dst[idx] = f2fp8(v * SW);
    }
}

__global__ void k_pack_wd(const float* Wd, fp8* dst) {
    const size_t n = (size_t)WDR * KDd;
    for (size_t i = (size_t)blockIdx.x * blockDim.x + threadIdx.x; i < n;
         i += (size_t)gridDim.x * blockDim.x) {
        int r = (int)(i / KDd), k = (int)(i % KDd);
        float v = (r < Fdim) ? Wd[(size_t)r * KDd + k] : 0.f;
        dst[i] = f2fp8(v * SW);
    }
}

// biases in the new 32-row packed order
__global__ void k_pack_bias(const float* bi1, const float* bh1,
                            const float* bi2, const float* bh2,
                            const float* bi3, const float* bh3,
                            const float* bd,
                            float* B1, float* B2, float* B3, float* BD) {
    const int n = 3 * NG + WDR;
    for (int i = blockIdx.x * blockDim.x + threadIdx.x; i < n;
         i += gridDim.x * blockDim.x) {
        if (i < NG)            { int ro = orig_row2(i);        B1[i]        = bi1[ro] + bh1[ro]; }
        else if (i < 2 * NG)   { int ro = orig_row2(i - NG);   B2[i - NG]   = bi2[ro] + bh2[ro]; }
        else if (i < 3 * NG)   { int ro = orig_row2(i - 2*NG); B3[i - 2*NG] = bi3[ro] + bh3[ro]; }
        else { int r = i - 3 * NG; BD[r] = (r < Fdim) ? bd[r] : 0.f; }
    }
}

// b1g = b1 + W1x @ bd  (exact f32), new packed order
__global__ void k_pack_b1g(const float* bi1, const float* bh1,
                           const float* Wih, const float* bd, float* B1G) {
    for (int pr = blockIdx.x * blockDim.x + threadIdx.x; pr < NG;
         pr += gridDim.x * blockDim.x) {
        int ro = orig_row2(pr);
        float acc = bi1[ro] + bh1[ro];
        for (int f = 0; f < Fdim; ++f)
            acc += Wih[(size_t)ro * Fdim + f] * bd[f];
        B1G[pr] = acc;
    }
}

// zero all rotating state slots with coherent stores (no cached copies anywhere)
__global__ void k_init(fp8* ab1, fp8* ab2, fp8* ab3, float* cb, unsigned* bar, int D) {
    const size_t n1 = (size_t)D * (S1e / 8);   // u64 count
    const size_t n2 = (size_t)D * (S2e / 8);
    const size_t nc = 3 * Bn * Hdim;
    const size_t tot = n1 + 2 * n2 + nc + 8192;
    for (size_t i = (size_t)blockIdx.x * blockDim.x + threadIdx.x; i < tot;
         i += (size_t)gridDim.x * blockDim.x) {
        if (i < n1)             stu64((unsigned long long*)ab1 + i, 0ull);
        else if (i < n1 + n2)   stu64((unsigned long long*)ab2 + (i - n1), 0ull);
        else if (i < n1 + 2*n2) stu64((unsigned long long*)ab3 + (i - n1 - n2), 0ull);
        else if (i < n1 + 2*n2 + nc) cb[i - n1 - 2*n2] = 0.f;
        else bar[i - n1 - 2*n2 - nc] = 0u;
    }
}

// stage x(0) into slot 0 (tiled layout), coherent, scaled by SA
__global__ void k_stage0(const float* xseq, fp8* ab1, int T0) {
    for (int idx = blockIdx.x * blockDim.x + threadIdx.x; idx < Bn * 11 * 16;
         idx += gridDim.x * blockDim.x) {
        int fu = idx >> 9, rem = idx & 511, b = rem >> 4, jj = rem & 15;
        int f = fu * 16 + jj;
        if (f < Fdim)
            st1c(&ab1[idx], f2fp8(xseq[(size_t)b * T0 * Fdim + f] * SA));
    }
}

__global__ void k_copy_orig(const float* xseq, float* out, int T, int T0) {
    const int n = Bn * T0 * Fdim;
    const size_t base = (size_t)Bn * T * Fdim;
    for (int i = blockIdx.x * blockDim.x + threadIdx.x; i < n;
         i += gridDim.x * blockDim.x) {
        out[base + i] = xseq[i];
    }
}

// ---------------- persistent LSTM kernel ----------------
// grid = 396 x 256 (4 waves), 2 blocks/CU co-resident: while one block waits
// on its producer poll, the co-resident block computes -> sync latency hides.
// Workers: bid<384 -> (layer = bid/128, ut2 = bid%128), 32 gate rows each.
// bid in [384,395): dedicated decoder blocks (off the recurrence).
// bid 395: aggregator (3 waves scan 128 worker flags each, publish LP x8).
__global__ __launch_bounds__(256, 2) void k_lstm(
    const float* __restrict__ xseq, float* __restrict__ out,
    const fp8* __restrict__ W1, const fp8* __restrict__ W1G,
    const fp8* __restrict__ W2, const fp8* __restrict__ W3,
    const fp8* __restrict__ WD,
    const float* __restrict__ b1, const float* __restrict__ b1g,
    const float* __restrict__ b2, const float* __restrict__ b3,
    const float* __restrict__ bdp,
    fp8* ab1, fp8* ab2, fp8* ab3, float* cb,
    unsigned* bar, int T0, int T, int dm) {
    __shared__ float red[4][32][34];
    __shared__ fp8 hstage[256];
    __shared__ fp8 xstage[5632];

    const int tid = threadIdx.x;
    const int w = tid >> 6;
    const int lane = tid & 63;
    const int bid = blockIdx.x;
    const int col = lane & 15;
    const int kb8 = (lane >> 4) << 3;

    // ---------------- aggregator ----------------
    if (bid == NWRK + NDEC) {
        if (w < 3) {
            unsigned tgt = 1;
            const unsigned* f0 = &bar[FLG(w * BPL + lane)];
            const unsigned* f1 = &bar[FLG(w * BPL + 64 + lane)];
            while (tgt <= (unsigned)T) {
                unsigned v0 = ldflag(f0), v1 = ldflag(f1);
                if (__all(v0 >= tgt && v1 >= tgt)) {
                    if (lane < 8) stflag(&bar[LPW(w, lane)], tgt);
                    ++tgt;
                } else {
                    __builtin_amdgcn_s_sleep(1);
                }
            }
        }
        return;
    }

    const int mir = bid & 7;

    // ---------------- dedicated decoder blocks ----------------
    if (bid >= NWRK) {
        const int dnt = bid - NWRK;
        const fp8* Wrowd = WD + (size_t)(dnt * 16) * KDd;
        for (int t = 0; t < T; ++t) {
            const int ns = (t + 1) & dm;
            pollLP(bar, 2, -1, (unsigned)(t + 1), lane, mir);
            const fp8* Ad = ab3 + (size_t)ns * S2e + 64 * 512;
            long d0[8], d1[8];
            aload<8>(Ad, w * 256, col, kb8, d0, d1);
            f32x4 dacc[2] = {};
#pragma unroll
            for (int i = 0; i < 8; ++i) {
                long bq = ld8b(Wrowd + (size_t)col * KDd + w * 256 + i * 32 + kb8);
                dacc[0] = mfma8(d0[i], bq, dacc[0]);
                dacc[1] = mfma8(d1[i], bq, dacc[1]);
            }
            __syncthreads();
#pragma unroll
            for (int mt = 0; mt < 2; ++mt)
#pragma unroll
                for (int r = 0; r < 4; ++r)
                    red[w][mt * 16 + (lane >> 4) * 4 + r][col] = dacc[mt][r];
            __syncthreads();
#pragma unroll
            for (int h = 0; h < 2; ++h) {
                int idx = h * 256 + tid;
                int b = idx >> 4, jj = idx & 15;
                int f = dnt * 16 + jj;
                float v = 0.f;
#pragma unroll
                for (int ww = 0; ww < 4; ++ww) v += red[ww][b][jj];
                v = v * INVS + bdp[f];
                if (f < Fdim)
                    out[(size_t)b * ((size_t)T * Fdim) + (size_t)t * Fdim + f] = v;
            }
            __syncthreads();
        }
        return;
    }

    // ---------------- worker blocks ----------------
    const int layer = bid >> 7;         // 0,1,2
    const int ut2 = bid & 127;          // 8-hidden-unit tile

    // elementwise mapping: thread -> (b = tid/8, u = tid%8)
    const int eb = tid >> 3;
    const int eu = tid & 7;

    // publish destinations
    fp8* dst0s = (layer == 0) ? ab1 : (layer == 1) ? ab2 : ab3;
    const size_t d0off = ((layer == 0) ? (size_t)(16 + (ut2 >> 1))
                                       : (size_t)(64 + (ut2 >> 1))) * 512 +
                         (size_t)(ut2 & 1) * 8;
    const size_t d0slot = (layer == 0) ? (size_t)S1e : (size_t)S2e;
    fp8* dst1s = (layer == 0) ? ab2 : (layer == 1) ? ab3 : nullptr;
    const size_t d1off = (size_t)(ut2 >> 1) * 512 + (size_t)(ut2 & 1) * 8;

    for (int t = 0; t < T; ++t) {
        const int st = t & dm;
        const int ns = (t + 1) & dm;

        // ---------- per-wave LP wait + A load + gate GEMM ----------
        f32x4 acc[2][2] = {};
        if (layer == 0 && t < T0) {
            pollLP(bar, 0, -1, (unsigned)t, lane, mir);
            const fp8* As = ab1 + (size_t)st * S1e;
            long a0[12], a1[12];
            aload<12>(As, w * 384, col, kb8, a0, a1);   // k>=1280 reads are
            wstream_pk<6>(W1 + (size_t)ut2 * 32 * K1K + (size_t)w * 8 * K1K,
                          lane, a0, a1, acc);           // benign (0-weights)
        } else if (layer == 0) {
            pollLP(bar, 2, 0, (unsigned)t, lane, mir);
            const fp8* Ah = (w < 2) ? ab3 + (size_t)st * S2e + 64 * 512
                                    : ab1 + (size_t)st * S1e + 16 * 512;
            long a0[16], a1[16];
            aload<16>(Ah, (w & 1) * 512, col, kb8, a0, a1);
            wstream_pk<8>(W1G + (size_t)ut2 * 32 * K1g + (size_t)w * 8 * K1g,
                          lane, a0, a1, acc);
        } else if (layer == 1) {
            pollLP(bar, 0, 1, (unsigned)t, lane, mir);
            const fp8* As = ab2 + (size_t)st * S2e;
            long a0[16], a1[16];
            aload<16>(As, w * 512, col, kb8, a0, a1);
            wstream_pk<8>(W2 + (size_t)ut2 * 32 * K2c + (size_t)w * 8 * K2c,
                          lane, a0, a1, acc);
        } else {
            pollLP(bar, 1, 2, (unsigned)t, lane, mir);
            const fp8* As = ab3 + (size_t)st * S2e;
            long a0[16], a1[16];
            aload<16>(As, w * 512, col, kb8, a0, a1);
            wstream_pk<8>(W3 + (size_t)ut2 * 32 * K2c + (size_t)w * 8 * K2c,
                          lane, a0, a1, acc);
        }

        __syncthreads();   // red[] free (previous readers done)
#pragma unroll
        for (int mt = 0; mt < 2; ++mt)
#pragma unroll
            for (int q2 = 0; q2 < 2; ++q2)
#pragma unroll
                for (int r = 0; r < 4; ++r)
                    red[w][mt * 16 + (lane >> 4) * 4 + r][q2 * 16 + col] = acc[mt][q2][r];
        __syncthreads();

        {   // gates + elementwise c/h update -> hstage (LDS)
            const float* bl = (layer == 0) ? ((t >= T0) ? b1g : b1)
                                           : (layer == 1) ? b2 : b3;
            float s[4];
#pragma unroll
            for (int g = 0; g < 4; ++g) {
                float a = 0.f;
#pragma unroll
                for (int ww = 0; ww < 4; ++ww) a += red[ww][eb][g * 8 + eu];
                s[g] = a * INVS + bl[ut2 * 32 + g * 8 + eu];
            }
            size_t cidx = ((size_t)layer * Bn + eb) * Hdim + ut2 * 8 + eu;
            float cold = cb[cidx];
            float cn = sigm(s[1]) * cold + sigm(s[0]) * ftanh(s[2]);
            float hn = sigm(s[3]) * ftanh(cn);
            cb[cidx] = cn;
            hstage[eb * 8 + eu] = f2fp8(hn * SA);
        }

        if (bid == 11 && t + 1 < T0) {  // stage conditioned x(t+1) into LDS
            for (int idx = tid; idx < Bn * 11 * 16; idx += 256) {
                int fu = idx >> 9, rem = idx & 511, b = rem >> 4, jj = rem & 15;
                int f = fu * 16 + jj;
                xstage[idx] = (f < Fdim)
                    ? f2fp8(xseq[((size_t)b * T0 + t + 1) * Fdim + f] * SA)
                    : (fp8)0;
            }
        }

        __syncthreads();   // hstage/xstage complete

        // ---------- wide coherent publish (8B per batch row) ----------
        if (tid < 32) {
            unsigned long long v =
                *reinterpret_cast<unsigned long long*>(&hstage[tid * 8]);
            stu64((unsigned long long*)(dst0s + (size_t)ns * d0slot + d0off + (size_t)tid * 16), v);
        } else if (tid < 64 && dst1s != nullptr) {
            int b = tid - 32;
            unsigned long long v =
                *reinterpret_cast<unsigned long long*>(&hstage[b * 8]);
            stu64((unsigned long long*)(dst1s + (size_t)ns * S2e + d1off + (size_t)b * 16), v);
        }
        if (bid == 11 && t + 1 < T0) {
            fp8* dst = ab1 + (size_t)ns * S1e;
            for (int i8 = tid; i8 < 704; i8 += 256) {
                unsigned long long xv =
                    *reinterpret_cast<unsigned long long*>(&xstage[i8 * 8]);
                stu64((unsigned long long*)(dst + i8 * 8), xv);
            }
        }

        __syncthreads();   // drain publish stores (vmcnt 0 at barrier)
        if (tid == 0) stflag(&bar[FLG(bid)], (unsigned)(t + 1));
    }
}

// ---------------- host launch ----------------
extern "C" void kernel_launch(void* const* d_in, const int* in_sizes, int n_in,
                              void* d_out, int out_size, void* d_ws, size_t ws_size,
                              hipStream_t stream) {
    const float* xseq = (const float*)d_in[0];
    const float* Wih1 = (const float*)d_in[2];
    const float* Whh1 = (const float*)d_in[3];
    const float* bih1 = (const float*)d_in[4];
    const float* bhh1 = (const float*)d_in[5];
    const float* Wih2 = (const float*)d_in[6];
    const float* Whh2 = (const float*)d_in[7];
    const float* bih2 = (const float*)d_in[8];
    const float* bhh2 = (const float*)d_in[9];
    const float* Wih3 = (const float*)d_in[10];
    const float* Whh3 = (const float*)d_in[11];
    const float* bih3 = (const float*)d_in[12];
    const float* bhh3 = (const float*)d_in[13];
    const float* Wd   = (const float*)d_in[14];
    const float* bd   = (const float*)d_in[15];

    const int T0 = in_sizes[0] / (Bn * Fdim);                 // 50
    const int T  = out_size / (Bn * Fdim) - T0;               // 350

    char* ws = (char*)d_ws;
    fp8*   pW1  = (fp8*)(ws + OFF_W1);
    fp8*   pW1G = (fp8*)(ws + OFF_W1G);
    fp8*   pW2  = (fp8*)(ws + OFF_W2);
    fp8*   pW3  = (fp8*)(ws + OFF_W3);
    fp8*   pWD  = (fp8*)(ws + OFF_WD);
    float* pB1  = (float*)(ws + OFF_B1);
    float* pB1G = (float*)(ws + OFF_B1G);
    float* pB2  = (float*)(ws + OFF_B2);
    float* pB3  = (float*)(ws + OFF_B3);
    float* pBD  = (float*)(ws + OFF_BD);
    float* cbp  = (float*)(ws + OFF_CB);
    unsigned* bar = (unsigned*)(ws + OFF_BAR);
    float* out = (float*)d_out;

    // rotation depth: largest power-of-2 D (<=32) whose state fits in ws
    int D = 32;
    while (D > 4 &&
           OFF_AB1 + (size_t)D * ((size_t)S1e + 2 * (size_t)S2e) > ws_size)
        D >>= 1;
    fp8* ab1 = (fp8*)(ws + OFF_AB1);
    fp8* ab2 = ab1 + (size_t)D * S1e;
    fp8* ab3 = ab2 + (size_t)D * S2e;

    (void)n_in;  // total need @D=32 ~= 38 MB

    hipLaunchKernelGGL(k_pack_pk, dim3(1024), dim3(256), 0, stream,
                       0, Wih1, Whh1, Wd, pW1, K1K);
    hipLaunchKernelGGL(k_pack_pk, dim3(4096), dim3(256), 0, stream,
                       1, Wih1, Whh1, Wd, pW1G, K1g);
    hipLaunchKernelGGL(k_pack_pk, dim3(1024), dim3(256), 0, stream,
                       2, Wih2, Whh2, Wd, pW2, K2c);
    hipLaunchKernelGGL(k_pack_pk, dim3(1024), dim3(256), 0, stream,
                       2, Wih3, Whh3, Wd, pW3, K2c);
    hipLaunchKernelGGL(k_pack_wd, dim3(704), dim3(256), 0, stream, Wd, pWD);
    hipLaunchKernelGGL(k_pack_bias, dim3(49), dim3(256), 0, stream,
                       bih1, bhh1, bih2, bhh2, bih3, bhh3, bd, pB1, pB2, pB3, pBD);
    hipLaunchKernelGGL(k_pack_b1g, dim3(16), dim3(256), 0, stream,
                       bih1, bhh1, Wih1, bd, pB1G);
    hipLaunchKernelGGL(k_init, dim3(2048), dim3(256), 0, stream,
                       ab1, ab2, ab3, cbp, bar, D);
    hipLaunchKernelGGL(k_stage0, dim3(22), dim3(256), 0, stream, xseq, ab1, T0);
    hipLaunchKernelGGL(k_lstm, dim3(NWRK + NDEC + 1), dim3(256), 0, stream,
                       xseq, out, pW1, pW1G, pW2, pW3, pWD,
                       pB1, pB1G, pB2, pB3, pBD,
                       ab1, ab2, ab3, cbp, bar, T0, T, D - 1);
    hipLaunchKernelGGL(k_copy_orig, dim3(1069), dim3(256), 0, stream, xseq, out, T, T0);
}

// Round 15
// 2568.534 us; speedup vs baseline: 1.1385x; 1.1385x over previous
//
#include <hip/hip_runtime.h>
#include <hip/hip_bf16.h>
#include <hip/hip_fp8.h>

// Problem constants (fixed by the bench: B=32, T0=50, F=171, H=1024, G=300)
#define Bn   32
#define Fdim 171
#define XPAD 256             // x-region padded to 16 tiles of 16 (conditioned phase)
#define Hdim 1024
#define NG   4096            // 4*H gate rows
#define K1K  1536            // layer1 conditioned K padded (x|pad|h|pad), 6 chunks/wave
#define K1g  2048            // layer1 generative K = H(h2 via Wcomb) + H(h0)
#define K2c  2048            // layer2/3 K = 2H
#define KDd  1024            // decoder K = H
#define WDR  176             // decoder rows padded 171 -> 176
#define NBLK 192             // worker blocks: 3 layers x 64 unit-tiles (+1 aggregator)
#define S1e  (80 * 512)      // ab1 slot BYTES (fp8, tiled [80][32][16], k<1280)
#define S2e  (128 * 512)     // ab2/ab3 slot BYTES (tiled [128][32][16])

// fp8 scaling: weights *64, activations *16, both exact powers of 2.
#define SW    64.0f
#define SA    16.0f
#define INVS  (1.0f / (SW * SA))

typedef __attribute__((ext_vector_type(4))) float f32x4;
typedef __attribute__((ext_vector_type(2))) long lx2;
typedef unsigned char fp8;

// ---------------- static workspace layout (bytes); ab buffers are tail ----
#define ALIGN256(x) ((((size_t)(x)) + 255) & ~(size_t)255)
constexpr size_t OFF_W1  = 0;                                       // packed, 4096*1536
constexpr size_t OFF_W1G = ALIGN256(OFF_W1 + (size_t)NG * K1K);     // packed, 4096*2048
constexpr size_t OFF_W2  = ALIGN256(OFF_W1G + (size_t)NG * K1g);
constexpr size_t OFF_W3  = ALIGN256(OFF_W2 + (size_t)NG * K2c);
constexpr size_t OFF_WD  = ALIGN256(OFF_W3 + (size_t)NG * K2c);     // old row-linear
constexpr size_t OFF_B1  = ALIGN256(OFF_WD + (size_t)WDR * KDd);
constexpr size_t OFF_B1G = ALIGN256(OFF_B1 + (size_t)NG * 4);
constexpr size_t OFF_B2  = ALIGN256(OFF_B1G + (size_t)NG * 4);
constexpr size_t OFF_B3  = ALIGN256(OFF_B2 + (size_t)NG * 4);
constexpr size_t OFF_BD  = ALIGN256(OFF_B3 + (size_t)NG * 4);
constexpr size_t OFF_CB  = ALIGN256(OFF_BD + (size_t)WDR * 4);
constexpr size_t OFF_BAR = ALIGN256(OFF_CB + (size_t)3 * Bn * Hdim * 4);
constexpr size_t OFF_AB1 = ALIGN256(OFF_BAR + 16384);   // bar region: 4096 u32

// flags: one u32 per 64B line. flag[b]=t+1 <=> block b finished step t.
#define FLG(i)   ((i) * 16)                 // 192 arrival flags
#define LPW(l,m) (3072 + ((l) * 4 + (m)) * 16)   // per-layer progress, 4 mirrors

// gate-interleaved packed row: pr = u*64 + q*16 + rr  <->  orig row = q*1024 + u*16 + rr
__device__ __forceinline__ int orig_row(int pr) {
    int u = pr >> 6, q = (pr >> 4) & 3, rr = pr & 15;
    return q * Hdim + u * 16 + rr;
}

__device__ __forceinline__ float sigm(float x) { return 1.f / (1.f + __expf(-x)); }
__device__ __forceinline__ float ftanh(float x) {   // overflow-safe fast tanh
    float e = __expf(-2.f * fabsf(x));
    float t = (1.f - e) / (1.f + e);
    return x >= 0.f ? t : -t;
}

__device__ __forceinline__ unsigned char f2fp8(float x) {  // OCP e4m3, RNE+sat
    __hip_fp8_e4m3 q(x);
    return (unsigned char)q.__x;
}

__device__ __forceinline__ long ld8b(const fp8* p) {   // plain cached 8B load
    return *reinterpret_cast<const long*>(p);
}
// Coherent write-through ops (agent scope, relaxed): no cache-wide maintenance.
__device__ __forceinline__ void st1c(fp8* p, unsigned char v) {
    __hip_atomic_store((unsigned char*)p, v, __ATOMIC_RELAXED, __HIP_MEMORY_SCOPE_AGENT);
}
__device__ __forceinline__ void stu64(unsigned long long* p, unsigned long long v) {
    __hip_atomic_store(p, v, __ATOMIC_RELAXED, __HIP_MEMORY_SCOPE_AGENT);
}
__device__ __forceinline__ unsigned ldflag(const unsigned* p) {
    return __hip_atomic_load(p, __ATOMIC_RELAXED, __HIP_MEMORY_SCOPE_AGENT);
}
__device__ __forceinline__ void stflag(unsigned* p, unsigned v) {
    __hip_atomic_store(p, v, __ATOMIC_RELAXED, __HIP_MEMORY_SCOPE_AGENT);
}
__device__ __forceinline__ f32x4 mfma8(long a, long b, f32x4 c) {
    return __builtin_amdgcn_mfma_f32_16x16x32_fp8_fp8(a, b, c, 0, 0, 0);
}

// A-fragment loads from tiled [k/16][b][16] fp8 state
template <int NF>
__device__ __forceinline__ void aload(const fp8* __restrict__ As, int k0,
                                      int col, int kb8, long (&a0)[NF], long (&a1)[NF]) {
#pragma unroll
    for (int i = 0; i < NF; ++i) {
        int k = k0 + i * 32 + kb8;
        const fp8* ap = As + (size_t)(k >> 4) * 512 + (k & 15);
        a0[i] = ld8b(ap + col * 16);
        a1[i] = ld8b(ap + (col + 16) * 16);
    }
}

// packed weight stream: per (i2,q) ONE 16B/lane load = 1KB/wave fully-used
// (two K-chunks per instruction) -> half the L2 line-requests of the row-
// scattered 8B loads.
template <int NP>
__device__ __forceinline__ void wstream_pk(const fp8* __restrict__ wwave, int lane,
                                           const long (&a0)[2 * NP],
                                           const long (&a1)[2 * NP],
                                           f32x4 (&acc)[2][4]) {
#pragma unroll
    for (int i2 = 0; i2 < NP; ++i2) {
        const fp8* p = wwave + i2 * 4096 + lane * 16;
#pragma unroll
        for (int q = 0; q < 4; ++q) {
            lx2 wv = *reinterpret_cast<const lx2*>(p + q * 1024);
            acc[0][q] = mfma8(a0[2 * i2],     wv[0], acc[0][q]);
            acc[1][q] = mfma8(a1[2 * i2],     wv[0], acc[1][q]);
            acc[0][q] = mfma8(a0[2 * i2 + 1], wv[1], acc[0][q]);
            acc[1][q] = mfma8(a1[2 * i2 + 1], wv[1], acc[1][q]);
        }
    }
}

// ---------------- prep kernels ----------------
// fragment-order packer. dst[idx]: idx = ut*(64*Kpk) + w*(8*Kpk) + i2*4096
//   + q*1024 + lane*16 + b ; holds W[row=ut*64+q*16+(lane&15)]
//   [k = w*(Kpk/8) + (2*i2+(b>>3))*32 + (lane>>4)*8 + (b&7)]
// mode 0: W1 conditioned (x|pad|h|pad), 1: W1G (Wcomb|Whh1), 2: W2/W3 (Wih|Whh)
__global__ void k_pack_pk(int mode, const float* Wih, const float* Whh,
                          const float* Wd, fp8* dst, int Kpk) {
    const size_t n = (size_t)NG * Kpk;
    const int kq = Kpk >> 3;
    for (size_t idx = (size_t)blockIdx.x * blockDim.x + threadIdx.x; idx < n;
         idx += (size_t)gridDim.x * blockDim.x) {
        int ut = (int)(idx / ((size_t)64 * Kpk));
        int rem = (int)(idx % ((size_t)64 * Kpk));
        int w = rem / (8 * Kpk);
        int rem2 = rem % (8 * Kpk);
        int i2 = rem2 >> 12;
        int q = (rem2 >> 10) & 3;
        int lane = (rem2 >> 4) & 63;
        int b = rem2 & 15;
        int ro = orig_row(ut * 64 + q * 16 + (lane & 15));
        int k = w * kq + (2 * i2 + (b >> 3)) * 32 + ((lane >> 4) << 3) + (b & 7);
        float v = 0.f;
        if (mode == 0) {
            if (k < Fdim) v = Wih[(size_t)ro * Fdim + k];
            else if (k >= XPAD && k < XPAD + Hdim) v = Whh[(size_t)ro * Hdim + (k - XPAD)];
        } else if (mode == 1) {
            if (k < Hdim) {
                float a = 0.f;
                for (int f = 0; f < Fdim; ++f)
                    a += Wih[(size_t)ro * Fdim + f] * Wd[(size_t)f * KDd + k];
                v = a;
            } else {
                v = Whh[(size_t)ro * Hdim + (k - 1024)];
            }
        } else {
            v = (k < Hdim) ? Wih[(size_t)ro * Hdim + k]
                           : Whh[(size_t)ro * Hdim + (k - Hdim)];
        }
        dst[idx] = f2fp8(v * SW);
    }
}

__global__ void k_pack_wd(const float* Wd, fp8* dst) {
    const size_t n = (size_t)WDR * KDd;
    for (size_t i = (size_t)blockIdx.x * blockDim.x + threadIdx.x; i < n;
         i += (size_t)gridDim.x * blockDim.x) {
        int r = (int)(i / KDd), k = (int)(i % KDd);
        float v = (r < Fdim) ? Wd[(size_t)r * KDd + k] : 0.f;
        dst[i] = f2fp8(v * SW);
    }
}

__global__ void k_pack_bias(const float* bi1, const float* bh1,
                            const float* bi2, const float* bh2,
                            const float* bi3, const float* bh3,
                            const float* bd,
                            float* B1, float* B2, float* B3, float* BD) {
    const int n = 3 * NG + WDR;
    for (int i = blockIdx.x * blockDim.x + threadIdx.x; i < n;
         i += gridDim.x * blockDim.x) {
        if (i < NG)            { int ro = orig_row(i);        B1[i]        = bi1[ro] + bh1[ro]; }
        else if (i < 2 * NG)   { int ro = orig_row(i - NG);   B2[i - NG]   = bi2[ro] + bh2[ro]; }
        else if (i < 3 * NG)   { int ro = orig_row(i - 2*NG); B3[i - 2*NG] = bi3[ro] + bh3[ro]; }
        else { int r = i - 3 * NG; BD[r] = (r < Fdim) ? bd[r] : 0.f; }
    }
}

// b1g = b1 + W1x @ bd  (exact f32)
__global__ void k_pack_b1g(const float* bi1, const float* bh1,
                           const float* Wih, const float* bd, float* B1G) {
    for (int pr = blockIdx.x * blockDim.x + threadIdx.x; pr < NG;
         pr += gridDim.x * blockDim.x) {
        int ro = orig_row(pr);
        float acc = bi1[ro] + bh1[ro];
        for (int f = 0; f < Fdim; ++f)
            acc += Wih[(size_t)ro * Fdim + f] * bd[f];
        B1G[pr] = acc;
    }
}

// zero all rotating state slots with coherent stores (no cached copies anywhere)
__global__ void k_init(fp8* ab1, fp8* ab2, fp8* ab3, float* cb, unsigned* bar, int D) {
    const size_t n1 = (size_t)D * (S1e / 8);   // u64 count
    const size_t n2 = (size_t)D * (S2e / 8);
    const size_t nc = 3 * Bn * Hdim;
    const size_t tot = n1 + 2 * n2 + nc + 4096;
    for (size_t i = (size_t)blockIdx.x * blockDim.x + threadIdx.x; i < tot;
         i += (size_t)gridDim.x * blockDim.x) {
        if (i < n1)             stu64((unsigned long long*)ab1 + i, 0ull);
        else if (i < n1 + n2)   stu64((unsigned long long*)ab2 + (i - n1), 0ull);
        else if (i < n1 + 2*n2) stu64((unsigned long long*)ab3 + (i - n1 - n2), 0ull);
        else if (i < n1 + 2*n2 + nc) cb[i - n1 - 2*n2] = 0.f;
        else bar[i - n1 - 2*n2 - nc] = 0u;
    }
}

// stage x(0) into slot 0 (tiled layout), coherent, scaled by SA
__global__ void k_stage0(const float* xseq, fp8* ab1, int T0) {
    for (int idx = blockIdx.x * blockDim.x + threadIdx.x; idx < Bn * 11 * 16;
         idx += gridDim.x * blockDim.x) {
        int fu = idx >> 9, rem = idx & 511, b = rem >> 4, jj = rem & 15;
        int f = fu * 16 + jj;
        if (f < Fdim)
            st1c(&ab1[idx], f2fp8(xseq[(size_t)b * T0 * Fdim + f] * SA));
    }
}

__global__ void k_copy_orig(const float* xseq, float* out, int T, int T0) {
    const int n = Bn * T0 * Fdim;
    const size_t base = (size_t)Bn * T * Fdim;
    for (int i = blockIdx.x * blockDim.x + threadIdx.x; i < n;
         i += gridDim.x * blockDim.x) {
        out[base + i] = xseq[i];
    }
}

// wave-0 poll: lane0 waits LP[la] >= tgt, lane1 waits LP[lb] >= tgt (mirror m)
__device__ __forceinline__ void pollLP(unsigned* bar, int la, int lb,
                                       unsigned tgt, int lane, int m) {
    for (;;) {
        bool ok = true;
        if (lane == 0) ok = (ldflag(&bar[LPW(la, m)]) >= tgt);
        else if (lane == 1 && lb >= 0) ok = (ldflag(&bar[LPW(lb, m)]) >= tgt);
        if (__all(ok)) break;
        __builtin_amdgcn_s_sleep(1);
    }
    asm volatile("" ::: "memory");
}

// ---------------- persistent LSTM kernel (aggregated dataflow sync) --------
// grid = NBLK+1 x 512. Workers: block -> (layer = bid/64, ut = bid%64).
// Block NBLK = aggregator: 3 waves continuously scan the 64 arrival flags of
// one layer each; when all >= tgt they publish LP[layer]=tgt to 4 mirrored
// lines and advance. Workers poll ONLY their 2 source-layer LP mirrors with
// 2 lanes (no global barrier; layers pipeline with skew <= 2; D=32 slots).
__global__ __launch_bounds__(512, 1) void k_lstm(
    const float* __restrict__ xseq, float* __restrict__ out,
    const fp8* __restrict__ W1, const fp8* __restrict__ W1G,
    const fp8* __restrict__ W2, const fp8* __restrict__ W3,
    const fp8* __restrict__ WD,
    const float* __restrict__ b1, const float* __restrict__ b1g,
    const float* __restrict__ b2, const float* __restrict__ b3,
    const float* __restrict__ bdp,
    fp8* ab1, fp8* ab2, fp8* ab3, float* cb,
    unsigned* bar, int T0, int T, int dm) {
    __shared__ float red[8][32][66];
    __shared__ fp8 hstage[512];
    __shared__ fp8 xstage[5632];

    const int tid = threadIdx.x;
    const int w = tid >> 6;
    const int lane = tid & 63;
    const int bid = blockIdx.x;

    // ---------------- aggregator block ----------------
    if (bid == NBLK) {
        if (w < 3) {
            unsigned tgt = 1;
            const unsigned* fp = &bar[FLG(64 * w + lane)];
            while (tgt <= (unsigned)T) {
                unsigned v = ldflag(fp);
                if (__all(v >= tgt)) {
                    if (lane < 4) stflag(&bar[LPW(w, lane)], tgt);
                    ++tgt;
                } else {
                    __builtin_amdgcn_s_sleep(1);
                }
            }
        }
        return;
    }

    const int col = lane & 15;
    const int kb8 = (lane >> 4) << 3;
    const int layer = bid >> 6;
    const int ut = bid & 63;
    const bool isdec = (bid >= 64 && bid < 75);
    const int dnt = bid - 64;

    // elementwise mapping (conflict-free dump + reduce)
    const int eb = w + 8 * (lane >> 4);
    const int ejj = lane & 15;
    const int off = eb * 16 + ejj;

    // publish destinations (block-constant)
    fp8* dst0s = (layer == 0) ? ab1 : (layer == 1) ? ab2 : ab3;
    const size_t d0off = (layer == 0) ? (size_t)(16 + ut) * 512
                                      : (size_t)(64 + ut) * 512;
    const size_t d0slot = (layer == 0) ? (size_t)S1e : (size_t)S2e;
    fp8* dst1s = (layer == 0) ? ab2 : (layer == 1) ? ab3 : nullptr;
    const size_t d1off = (size_t)ut * 512;

    for (int t = 0; t < T; ++t) {
        const int st = t & dm;
        const int ns = (t + 1) & dm;

        // ---------- wait for source layers (wave 0 only) ----------
        if (w == 0) {
            int la, lb = -1;
            if (layer == 0) { if (t < T0) { la = 0; } else { la = 2; lb = 0; } }
            else if (layer == 1) { la = 0; lb = 1; }
            else { la = 1; lb = 2; }
            pollLP(bar, la, lb, (unsigned)t, lane, bid & 3);
        }
        __syncthreads();

        // ---------- gate GEMM (packed weights) ----------
        f32x4 acc[2][4] = {};
        if (layer == 0) {
            if (t < T0) {
                const fp8* As = ab1 + (size_t)st * S1e;
                long a0[6], a1[6];
                aload<6>(As, w * (K1K / 8), col, kb8, a0, a1);
                wstream_pk<3>(W1 + (size_t)ut * 64 * K1K + (size_t)w * 8 * K1K,
                              lane, a0, a1, acc);
            } else {
                const fp8* Ah = (w < 4) ? ab3 + (size_t)st * S2e + 64 * 512
                                        : ab1 + (size_t)st * S1e + 16 * 512;
                long a0[8], a1[8];
                aload<8>(Ah, (w & 3) * 256, col, kb8, a0, a1);
                wstream_pk<4>(W1G + (size_t)ut * 64 * K1g + (size_t)w * 8 * K1g,
                              lane, a0, a1, acc);
            }
        } else if (layer == 1) {
            const fp8* As = ab2 + (size_t)st * S2e;
            long a0[8], a1[8];
            aload<8>(As, w * 256, col, kb8, a0, a1);
            wstream_pk<4>(W2 + (size_t)ut * 64 * K2c + (size_t)w * 8 * K2c,
                          lane, a0, a1, acc);
        } else {
            const fp8* As = ab3 + (size_t)st * S2e;
            long a0[8], a1[8];
            aload<8>(As, w * 256, col, kb8, a0, a1);
            wstream_pk<4>(W3 + (size_t)ut * 64 * K2c + (size_t)w * 8 * K2c,
                          lane, a0, a1, acc);
        }

        __syncthreads();
#pragma unroll
        for (int mt = 0; mt < 2; ++mt)
#pragma unroll
            for (int q = 0; q < 4; ++q)
#pragma unroll
                for (int r = 0; r < 4; ++r)
                    red[w][mt * 16 + (lane >> 4) * 4 + r][q * 16 + col] = acc[mt][q][r];
        __syncthreads();

        {   // gates + elementwise c/h update -> hstage (LDS)
            const float* bl = (layer == 0) ? ((t >= T0) ? b1g : b1)
                                           : (layer == 1) ? b2 : b3;
            float s[4];
#pragma unroll
            for (int q = 0; q < 4; ++q) {
                float a = 0.f;
#pragma unroll
                for (int ww = 0; ww < 8; ++ww) a += red[ww][eb][q * 16 + ejj];
                s[q] = a * INVS + bl[ut * 64 + q * 16 + ejj];
            }
            size_t cidx = ((size_t)layer * Bn + eb) * Hdim + ut * 16 + ejj;
            float cold = cb[cidx];
            float cn = sigm(s[1]) * cold + sigm(s[0]) * ftanh(s[2]);
            float hn = sigm(s[3]) * ftanh(cn);
            cb[cidx] = cn;
            hstage[off] = f2fp8(hn * SA);
        }

        if (bid == 11 && t + 1 < T0) {  // stage conditioned x(t+1) via LDS
            for (int idx = tid; idx < Bn * 11 * 16; idx += 512) {
                int fu = idx >> 9, rem = idx & 511, b = rem >> 4, jj = rem & 15;
                int f = fu * 16 + jj;
                xstage[idx] = (f < Fdim)
                    ? f2fp8(xseq[((size_t)b * T0 + t + 1) * Fdim + f] * SA)
                    : (fp8)0;
            }
        }

        __syncthreads();  // hstage/xstage complete

        // wide coherent publish (8B stores)
        if (tid < 64) {
            unsigned long long v =
                *reinterpret_cast<unsigned long long*>(&hstage[tid * 8]);
            stu64((unsigned long long*)(dst0s + (size_t)ns * d0slot + d0off + tid * 8), v);
        } else if (tid < 128 && dst1s != nullptr) {
            unsigned long long v =
                *reinterpret_cast<unsigned long long*>(&hstage[(tid - 64) * 8]);
            stu64((unsigned long long*)(dst1s + (size_t)ns * S2e + d1off + (tid - 64) * 8), v);
        }
        if (bid == 11 && t + 1 < T0 && tid < 128) {
            fp8* dst = ab1 + (size_t)ns * S1e;
            for (int i8 = tid; i8 < 704; i8 += 128) {
                unsigned long long v =
                    *reinterpret_cast<unsigned long long*>(&xstage[i8 * 8]);
                stu64((unsigned long long*)(dst + i8 * 8), v);
            }
        }

        __syncthreads();  // drain publish stores (vmcnt 0 at barrier)
        if (tid == 0) stflag(&bar[FLG(bid)], (unsigned)(t + 1));

        // ---------- decoder (blocks 64..74): out(t) = h2(t) @ Wd^T + bd ----------
        if (isdec) {
            if (w == 0) pollLP(bar, 2, -1, (unsigned)(t + 1), lane, bid & 3);
            __syncthreads();
            const fp8* Ad = ab3 + (size_t)ns * S2e + 64 * 512;
            const fp8* Wrowd = WD + (size_t)(dnt * 16) * KDd;
            long d0[4], d1[4];
            aload<4>(Ad, w * 128, col, kb8, d0, d1);
            f32x4 dacc[2] = {};
#pragma unroll
            for (int i = 0; i < 4; ++i) {
                long bq = ld8b(Wrowd + (size_t)col * KDd + w * 128 + i * 32 + kb8);
                dacc[0] = mfma8(d0[i], bq, dacc[0]);
                dacc[1] = mfma8(d1[i], bq, dacc[1]);
            }
            __syncthreads();
#pragma unroll
            for (int mt = 0; mt < 2; ++mt)
#pragma unroll
                for (int r = 0; r < 4; ++r)
                    red[w][mt * 16 + (lane >> 4) * 4 + r][col] = dacc[mt][r];
            __syncthreads();
            {
                int f = dnt * 16 + ejj;
                float v = 0.f;
#pragma unroll
                for (int ww = 0; ww < 8; ++ww) v += red[ww][eb][ejj];
                v = v * INVS + bdp[f];
                if (f < Fdim)
                    out[(size_t)eb * ((size_t)T * Fdim) + (size_t)t * Fdim + f] = v;
            }
        }
    }
}

// ---------------- host launch ----------------
extern "C" void kernel_launch(void* const* d_in, const int* in_sizes, int n_in,
                              void* d_out, int out_size, void* d_ws, size_t ws_size,
                              hipStream_t stream) {
    const float* xseq = (const float*)d_in[0];
    const float* Wih1 = (const float*)d_in[2];
    const float* Whh1 = (const float*)d_in[3];
    const float* bih1 = (const float*)d_in[4];
    const float* bhh1 = (const float*)d_in[5];
    const float* Wih2 = (const float*)d_in[6];
    const float* Whh2 = (const float*)d_in[7];
    const float* bih2 = (const float*)d_in[8];
    const float* bhh2 = (const float*)d_in[9];
    const float* Wih3 = (const float*)d_in[10];
    const float* Whh3 = (const float*)d_in[11];
    const float* bih3 = (const float*)d_in[12];
    const float* bhh3 = (const float*)d_in[13];
    const float* Wd   = (const float*)d_in[14];
    const float* bd   = (const float*)d_in[15];

    const int T0 = in_sizes[0] / (Bn * Fdim);                 // 50
    const int T  = out_size / (Bn * Fdim) - T0;               // 350

    char* ws = (char*)d_ws;
    fp8*   pW1  = (fp8*)(ws + OFF_W1);
    fp8*   pW1G = (fp8*)(ws + OFF_W1G);
    fp8*   pW2  = (fp8*)(ws + OFF_W2);
    fp8*   pW3  = (fp8*)(ws + OFF_W3);
    fp8*   pWD  = (fp8*)(ws + OFF_WD);
    float* pB1  = (float*)(ws + OFF_B1);
    float* pB1G = (float*)(ws + OFF_B1G);
    float* pB2  = (float*)(ws + OFF_B2);
    float* pB3  = (float*)(ws + OFF_B3);
    float* pBD  = (float*)(ws + OFF_BD);
    float* cbp  = (float*)(ws + OFF_CB);
    unsigned* bar = (unsigned*)(ws + OFF_BAR);
    float* out = (float*)d_out;

    // rotation depth: largest power-of-2 D (<=32) whose state fits in ws
    int D = 32;
    while (D > 4 &&
           OFF_AB1 + (size_t)D * ((size_t)S1e + 2 * (size_t)S2e) > ws_size)
        D >>= 1;
    fp8* ab1 = (fp8*)(ws + OFF_AB1);
    fp8* ab2 = ab1 + (size_t)D * S1e;
    fp8* ab3 = ab2 + (size_t)D * S2e;

    (void)n_in;  // total need @D=32 ~= 38 MB

    hipLaunchKernelGGL(k_pack_pk, dim3(1024), dim3(256), 0, stream,
                       0, Wih1, Whh1, Wd, pW1, K1K);
    hipLaunchKernelGGL(k_pack_pk, dim3(4096), dim3(256), 0, stream,
                       1, Wih1, Whh1, Wd, pW1G, K1g);
    hipLaunchKernelGGL(k_pack_pk, dim3(1024), dim3(256), 0, stream,
                       2, Wih2, Whh2, Wd, pW2, K2c);
    hipLaunchKernelGGL(k_pack_pk, dim3(1024), dim3(256), 0, stream,
                       2, Wih3, Whh3, Wd, pW3, K2c);
    hipLaunchKernelGGL(k_pack_wd, dim3(704), dim3(256), 0, stream, Wd, pWD);
    hipLaunchKernelGGL(k_pack_bias, dim3(49), dim3(256), 0, stream,
                       bih1, bhh1, bih2, bhh2, bih3, bhh3, bd, pB1, pB2, pB3, pBD);
    hipLaunchKernelGGL(k_pack_b1g, dim3(16), dim3(256), 0, stream,
                       bih1, bhh1, Wih1, bd, pB1G);
    hipLaunchKernelGGL(k_init, dim3(2048), dim3(256), 0, stream,
                       ab1, ab2, ab3, cbp, bar, D);
    hipLaunchKernelGGL(k_stage0, dim3(22), dim3(256), 0, stream, xseq, ab1, T0);
    hipLaunchKernelGGL(k_lstm, dim3(NBLK + 1), dim3(512), 0, stream,
                       xseq, out, pW1, pW1G, pW2, pW3, pWD,
                       pB1, pB1G, pB2, pB3, pBD,
                       ab1, ab2, ab3, cbp, bar, T0, T, D - 1);
    hipLaunchKernelGGL(k_copy_orig, dim3(1069), dim3(256), 0, stream, xseq, out, T, T0);
}